// Round 12
// baseline (2937.701 us; speedup 1.0000x reference)
//
#include <hip/hip_runtime.h>
#include <stdint.h>

// Bidirectional LSTM.  B=32, T=512, V=32000, D=300, U=300, NT=3.
// R12: exchange via self-validating TAGGED CHUNKS: producer packs
// (ts+1)<<32 | 2xbf16 into u64s, publishes its chunk with 2 coalesced
// stores/thread (no flag, no vmcnt, no drain barrier); consumer's coalesced
// 18-u64 burst IS the poll (retry stale slots only).  Own chunk stays in
// LDS.  H layout is chunk-major [p][b][32u] so MFMA K-tiles == chunks.
// 2 barriers/step.  zx/fc/preps from verified R8.

#define BB 32
#define TT 512
#define DD 300
#define UU 300
#define G4 1200   // 4*U
#define NTOK 3

#define KB   10    // rec blocks per direction
#define UPB  30    // units per rec block
#define NCOL 120   // gate-cols per rec block (4*UPB)
#define KTILES 10  // K-tiles == producer chunks (32 elems each, 30 real)
#define WRROW 302  // WrPT row length (300 real + 2 zero)
#define CROW 64    // Hlds padded row elems per (chunk,batch)
#define HSTR 320   // zx_gemm2 LDS row stride (unchanged from R8)

#define WKROWS 1280  // WkT padded p-rows
#define WKSTR  320   // WkT padded k-stride

typedef uint16_t bf16_t;
typedef short  s16x8 __attribute__((ext_vector_type(8)));
typedef float  f32x4 __attribute__((ext_vector_type(4)));

union U8 { unsigned long long q[2]; s16x8 v; };

__device__ __forceinline__ float bf2f(uint16_t u) {
    union { uint32_t i; float f; } v; v.i = ((uint32_t)u) << 16; return v.f;
}
__device__ __forceinline__ uint16_t f2bf(float f) {
    union { uint32_t i; float f; } v; v.f = f;
    uint32_t r = v.i + 0x7fffu + ((v.i >> 16) & 1u);   // RNE
    return (uint16_t)(r >> 16);
}
__device__ __forceinline__ float ldf(const void* base, size_t idx, int f32m) {
    return f32m ? ((const float*)base)[idx]
                : bf2f(((const uint16_t*)base)[idx]);
}

// 4x4 transpose across lane bits 0..1 (verified R7/R8)
__device__ __forceinline__ f32x4 xpose4(f32x4 v, int lane) {
    f32x4 t, w, s, r;
    t[0] = __shfl_xor(v[0], 1); t[1] = __shfl_xor(v[1], 1);
    t[2] = __shfl_xor(v[2], 1); t[3] = __shfl_xor(v[3], 1);
    if ((lane & 1) == 0) { w[0]=v[0]; w[1]=t[0]; w[2]=v[2]; w[3]=t[2]; }
    else                 { w[0]=t[1]; w[1]=v[1]; w[2]=t[3]; w[3]=v[3]; }
    s[0] = __shfl_xor(w[0], 2); s[1] = __shfl_xor(w[1], 2);
    s[2] = __shfl_xor(w[2], 2); s[3] = __shfl_xor(w[3], 2);
    if ((lane & 2) == 0) { r[0]=w[0]; r[1]=w[1]; r[2]=s[0]; r[3]=s[1]; }
    else                 { r[0]=s[2]; r[1]=s[3]; r[2]=w[2]; r[3]=w[3]; }
    return r;
}

__device__ __forceinline__ void gatefn(f32x4 zv, uint2 zp, bool m,
                                       float& c, float& h) {
    float zi = zv[0] + bf2f((uint16_t)(zp.x & 0xffff));
    float zf = zv[1] + bf2f((uint16_t)(zp.x >> 16));
    float zg = zv[2] + bf2f((uint16_t)(zp.y & 0xffff));
    float zo = zv[3] + bf2f((uint16_t)(zp.y >> 16));
    float si = 1.f / (1.f + __expf(-zi));
    float sf = 1.f / (1.f + __expf(-zf));
    float so = 1.f / (1.f + __expf(-zo));
    float tg = tanhf(zg);
    float cn = sf * c + si * tg;
    float hn = so * tanhf(cn);
    if (m) { c = cn; h = hn; }
}

// ---------------------------------------------------------------------------
// Kernel 0: dtype detector (f32 vs bf16 inputs).
// ---------------------------------------------------------------------------
__global__ void detect_dtype(const uint16_t* __restrict__ emb_u16,
                             int* __restrict__ flag) {
    __shared__ float red[256];
    const int tid = threadIdx.x;
    float m = 0.f;
    for (int k = tid; k < 4096; k += 256)
        m = fmaxf(m, fabsf(bf2f(emb_u16[2 * k])));
    red[tid] = m;
    __syncthreads();
    for (int s = 128; s > 0; s >>= 1) {
        if (tid < s) red[tid] = fmaxf(red[tid], red[tid + s]);
        __syncthreads();
    }
    if (tid == 0) flag[0] = (red[0] > 1.0e3f) ? 1 : 0;
}

// ---------------------------------------------------------------------------
// Kernel 1: build WrPT[dir][p][k] rows of WRROW=302 (k<300 real, 300,301=0).
// WrPT[p][k] = Wr[k][g*300+u], p = 4u+g.
// ---------------------------------------------------------------------------
__global__ void prep_wrp(const void* __restrict__ Wr_f,
                         const void* __restrict__ Wr_b,
                         bf16_t* __restrict__ WrPT_f,
                         bf16_t* __restrict__ WrPT_b,
                         const int* __restrict__ flagp) {
    const int f32m = *flagp;
    int idx = blockIdx.x * 256 + threadIdx.x;          // over 1200*302
    const void* src = blockIdx.y ? Wr_b : Wr_f;
    bf16_t*     dst = blockIdx.y ? WrPT_b : WrPT_f;
    if (idx < G4 * WRROW) {
        int p = idx / WRROW;
        int k = idx - p * WRROW;
        int u = p >> 2, g = p & 3;
        float v = (k < DD) ? ldf(src, (size_t)k * G4 + g * UU + u, f32m) : 0.f;
        dst[idx] = f2bf(v);
    }
}

// ---------------------------------------------------------------------------
// Kernel 1c: build WkT[dir][p][k] (zx weights, permuted+padded) + biasP.
// ---------------------------------------------------------------------------
__global__ void prep_wkt(const void* __restrict__ Wk_f, const void* __restrict__ b_f,
                         const void* __restrict__ Wk_b, const void* __restrict__ b_b,
                         bf16_t* __restrict__ WkT, bf16_t* __restrict__ biasP,
                         const int* __restrict__ flagp) {
    const int f32m = *flagp;
    const int dir = blockIdx.y;
    const void* Wk = dir ? Wk_b : Wk_f;
    const void* bs = dir ? b_b  : b_f;
    bf16_t* dst = WkT + (size_t)dir * (WKROWS * WKSTR);
    int idx = blockIdx.x * 256 + threadIdx.x;          // over 1280*320
    if (idx < WKROWS * WKSTR) {
        int p = idx / WKSTR;
        int k = idx - p * WKSTR;
        int u = p >> 2, g = p & 3;
        float v = (p < G4 && k < DD) ? ldf(Wk, (size_t)k * G4 + g * UU + u, f32m)
                                     : 0.f;
        dst[idx] = f2bf(v);
        if (idx < WKROWS) {
            int pp = idx, uu = pp >> 2, gg = pp & 3;
            biasP[dir * WKROWS + idx] =
                (pp < G4) ? f2bf(ldf(bs, gg * UU + uu, f32m)) : (bf16_t)0;
        }
    }
}

// ---------------------------------------------------------------------------
// Kernel 1b: zero tagged-chunk double-buffers (tag 0 never matches ts>=1).
// ---------------------------------------------------------------------------
__global__ void init_state(unsigned long long* __restrict__ Hgtag) {
    int i = blockIdx.x * 256 + threadIdx.x;
    if (i < 2 * 2 * KB * 512) Hgtag[i] = 0ull;
}

// ---------------------------------------------------------------------------
// Kernel 2: MFMA zx GEMM (verified R8, unchanged).
// ---------------------------------------------------------------------------
#define ZM 64
#define ZN 128
__global__ __launch_bounds__(256, 2) void zx_gemm2(
    const int* __restrict__ inputs, const void* __restrict__ emb,
    const bf16_t* __restrict__ WkTall, const bf16_t* __restrict__ biasP,
    bf16_t* __restrict__ zxf, bf16_t* __restrict__ zxb,
    const int* __restrict__ flagp) {

    const int f32m = *flagp;
    const int dir = blockIdx.z;
    const bf16_t* WkT = WkTall + (size_t)dir * (WKROWS * WKSTR);
    const bf16_t* bp  = biasP + dir * WKROWS;
    bf16_t* out = dir ? zxb : zxf;

    const int tid = threadIdx.x;
    const int pb = blockIdx.x * ZN;
    const int rowBase = blockIdx.y * ZM;

    __shared__ __align__(16) uint16_t Alds[ZM * HSTR];   // 40,960 B
    __shared__ int rowids[ZM];

    if (tid < ZM) rowids[tid] = inputs[rowBase + tid];
    for (int i = tid; i < ZM * HSTR; i += 256) Alds[i] = 0;
    __syncthreads();

    for (int i = tid; i < ZM * 38; i += 256) {
        int r = i / 38, g = i - 38 * r;
        int k0 = g * 8;
        const size_t eb = (size_t)rowids[r] * DD + k0;
        uint16_t tmp[8];
        if (g < 37) {
            if (f32m) {
                const float* ef = (const float*)emb + eb;
#pragma unroll
                for (int e = 0; e < 8; e++) tmp[e] = f2bf(ef[e]);
            } else {
                *(uint4*)tmp = *(const uint4*)((const uint16_t*)emb + eb);
            }
        } else {
#pragma unroll
            for (int e = 0; e < 8; e++) {
                int k = k0 + e;
                tmp[e] = (k < DD)
                    ? (f32m ? f2bf(((const float*)emb)[(size_t)rowids[r] * DD + k])
                            : ((const uint16_t*)emb)[(size_t)rowids[r] * DD + k])
                    : (uint16_t)0;
            }
        }
        *(uint4*)&Alds[r * HSTR + ((g ^ (r & 7)) << 3)] = *(uint4*)tmp;
    }
    __syncthreads();

    const int lane = tid & 63;
    const int wv   = tid >> 6;
    const int q    = lane >> 4;
    const int c16  = lane & 15;
    const int n0   = 32 * wv;
    const int sw7  = c16 & 7;

    f32x4 acc[4][2];
#pragma unroll
    for (int mt = 0; mt < 4; mt++)
        for (int nh = 0; nh < 2; nh++) acc[mt][nh] = (f32x4){0.f,0.f,0.f,0.f};

    const int p0 = pb + n0 + c16;
    const int p1 = p0 + 16;
#pragma unroll
    for (int kt = 0; kt < KTILES; kt++) {
        int k0 = 32 * kt + 8 * q;
        int sw = (((kt * 4 + q) ^ sw7) << 3);
        s16x8 b0 = *(const s16x8*)&WkT[(size_t)p0 * WKSTR + k0];
        s16x8 b1 = *(const s16x8*)&WkT[(size_t)p1 * WKSTR + k0];
#pragma unroll
        for (int mt = 0; mt < 4; mt++) {
            s16x8 af = *(const s16x8*)&Alds[(16 * mt + c16) * HSTR + sw];
            acc[mt][0] = __builtin_amdgcn_mfma_f32_16x16x32_bf16(af, b0, acc[mt][0], 0, 0, 0);
            acc[mt][1] = __builtin_amdgcn_mfma_f32_16x16x32_bf16(af, b1, acc[mt][1], 0, 0, 0);
        }
    }

    __syncthreads();
    float* Cs = (float*)Alds;           // [64][132] f32
#pragma unroll
    for (int mt = 0; mt < 4; mt++)
#pragma unroll
        for (int nh = 0; nh < 2; nh++)
#pragma unroll
            for (int r = 0; r < 4; r++)
                Cs[(16 * mt + 4 * q + r) * 132 + n0 + 16 * nh + c16] = acc[mt][nh][r];
    __syncthreads();

    for (int i = tid; i < ZM * (ZN / 2); i += 256) {
        int r = i >> 6, cc = (i & 63) * 2;
        int p = pb + cc;
        if (p < G4) {
            float v0 = Cs[r * 132 + cc]     + bf2f(bp[p]);
            float v1 = Cs[r * 132 + cc + 1] + bf2f(bp[p + 1]);
            uint32_t pk = (uint32_t)f2bf(v0) | ((uint32_t)f2bf(v1) << 16);
            *(uint32_t*)&out[(size_t)(rowBase + r) * G4 + p] = pk;
        }
    }
}

// ---------------------------------------------------------------------------
// Kernel 3: tagged-chunk MFMA recurrence.  20 blocks (10/dir), 256 thr.
// ---------------------------------------------------------------------------
__global__ __launch_bounds__(256, 1) void lstm_rec7(
    const bf16_t* __restrict__ zxf, const bf16_t* __restrict__ zxb,
    const bf16_t* __restrict__ WrPT_f, const bf16_t* __restrict__ WrPT_b,
    const int* __restrict__ seqlen,
    unsigned long long* __restrict__ Hgtag,
    bf16_t* __restrict__ hf, bf16_t* __restrict__ hb) {

    const int blk = blockIdx.x % KB;
    const int dir = blockIdx.x / KB;
    const bf16_t* zx   = dir ? zxb    : zxf;
    const bf16_t* WrPT = dir ? WrPT_b : WrPT_f;
    bf16_t*       hout = dir ? hb : hf;
    unsigned long long* Hg = Hgtag + (size_t)dir * (2 * KB * 512);

    __shared__ __align__(16) uint16_t Hlds[KB * BB * CROW];  // 40,960 B
    __shared__ __align__(16) uint16_t hstage[BB * 32];       //  2,048 B
    uint32_t* Hld32 = (uint32_t*)Hlds;

    const int tid  = threadIdx.x;
    const int lane = tid & 63;
    const int wv   = tid >> 6;
    const int q    = lane >> 4;
    const int c16  = lane & 15;
    const int n0   = 32 * wv;
    const int sw7  = c16 & 7;
    const int k4   = c16 >> 2;
    const int j4   = c16 & 3;
    const int u0   = 8 * wv + k4;
    const int b0   = 4 * q + j4;
    const bool v1  = (u0 + 4 < UPB);

    int plist[9];
#pragma unroll
    for (int i = 0; i < 9; i++) plist[i] = (i < blk) ? i : i + 1;

    // one-time init: zero Hlds + hstage (pads 30,31 must stay 0 forever),
    // B-frags to registers from 302-elem rows at offset 30*kt+8q.
    for (int i = tid; i < KB * BB * CROW; i += 256) Hlds[i] = 0;
    for (int i = tid; i < BB * 32; i += 256) hstage[i] = 0;
    U8 Bf0[KTILES], Bf1[KTILES];
#pragma unroll
    for (int kt = 0; kt < KTILES; kt++) {
        int koff = 30 * kt + 8 * q;
        int col0 = n0 + c16, col1 = n0 + 16 + c16;
        U8 z; z.q[0] = 0; z.q[1] = 0;
        Bf0[kt] = z; Bf1[kt] = z;
        if (col0 < NCOL)
            Bf0[kt].v = *(const s16x8*)&WrPT[(size_t)(NCOL * blk + col0) * WRROW + koff];
        if (col1 < NCOL)
            Bf1[kt].v = *(const s16x8*)&WrPT[(size_t)(NCOL * blk + col1) * WRROW + koff];
        // elements with k-index j>=30 multiply guaranteed-zero A pads — no mask
    }
    float c00 = 0.f, c01 = 0.f, c10 = 0.f, c11 = 0.f;
    float h00 = 0.f, h01 = 0.f, h10 = 0.f, h11 = 0.f;
    const int L0 = seqlen[b0];
    const int L1 = seqlen[b0 + 16];
    __syncthreads();

    for (int ts = 0; ts < TT; ts++) {
        const int t = dir ? (TT - 1 - ts) : ts;

        // zx prefetch (overlaps the tagged wait)
        const size_t zr0 = ((size_t)(b0 * TT + t)) * G4 + NCOL * blk;
        const size_t zr1 = ((size_t)((b0 + 16) * TT + t)) * G4 + NCOL * blk;
        uint2 z00 = *(const uint2*)&zx[zr0 + 4 * u0];
        uint2 z10 = *(const uint2*)&zx[zr1 + 4 * u0];
        uint2 z01 = {0, 0}, z11 = {0, 0};
        if (v1) {
            z01 = *(const uint2*)&zx[zr0 + 4 * (u0 + 4)];
            z11 = *(const uint2*)&zx[zr1 + 4 * (u0 + 4)];
        }

        if (ts > 0) {
            // tagged reload: the coalesced burst IS the poll
            const unsigned long long* Hsrc = Hg + (size_t)(ts & 1) * (KB * 512);
            const uint32_t tg = (uint32_t)ts;
            unsigned long long hv[18];
#pragma unroll
            for (int i = 0; i < 9; i++) {
                hv[2 * i]     = __hip_atomic_load(&Hsrc[plist[i] * 512 + tid],
                                    __ATOMIC_RELAXED, __HIP_MEMORY_SCOPE_AGENT);
                hv[2 * i + 1] = __hip_atomic_load(&Hsrc[plist[i] * 512 + 256 + tid],
                                    __ATOMIC_RELAXED, __HIP_MEMORY_SCOPE_AGENT);
            }
            uint32_t pend = 0;
#pragma unroll
            for (int i = 0; i < 18; i++)
                if ((uint32_t)(hv[i] >> 32) != tg) pend |= 1u << i;
            while (pend) {
#pragma unroll
                for (int i = 0; i < 18; i++) {
                    if (pend & (1u << i)) {
                        unsigned long long v = __hip_atomic_load(
                            &Hsrc[plist[i >> 1] * 512 + ((i & 1) << 8) + tid],
                            __ATOMIC_RELAXED, __HIP_MEMORY_SCOPE_AGENT);
                        if ((uint32_t)(v >> 32) == tg) {
                            hv[i] = v;
                            pend &= ~(1u << i);
                        }
                    }
                }
                if (pend) __builtin_amdgcn_s_sleep(1);
            }
            // scatter payloads into swizzled chunk-major Hlds (u32 writes)
#pragma unroll
            for (int i = 0; i < 18; i++) {
                int w = tid + ((i & 1) << 8);
                int b = w >> 4, j = w & 15;
                int p = plist[i >> 1];
                Hld32[p * 1024 + b * 32 + 4 * ((j >> 2) ^ (b & 7)) + (j & 3)] =
                    (uint32_t)hv[i];
            }
        }
        __syncthreads();                                  // (1)

        // MFMA: K-tile kt == chunk kt.  A rows c16 / c16+16, k = 8q..8q+8.
        f32x4 acc00 = {0.f,0.f,0.f,0.f}, acc01 = {0.f,0.f,0.f,0.f};
        f32x4 acc10 = {0.f,0.f,0.f,0.f}, acc11 = {0.f,0.f,0.f,0.f};
#pragma unroll
        for (int kt = 0; kt < KTILES; kt++) {
            int sw = 8 * (q ^ sw7);
            s16x8 a0 = *(const s16x8*)&Hlds[kt * 2048 + c16 * CROW + sw];
            s16x8 a1 = *(const s16x8*)&Hlds[kt * 2048 + (c16 + 16) * CROW + sw];
            acc00 = __builtin_amdgcn_mfma_f32_16x16x32_bf16(a0, Bf0[kt].v, acc00, 0, 0, 0);
            acc01 = __builtin_amdgcn_mfma_f32_16x16x32_bf16(a0, Bf1[kt].v, acc01, 0, 0, 0);
            acc10 = __builtin_amdgcn_mfma_f32_16x16x32_bf16(a1, Bf0[kt].v, acc10, 0, 0, 0);
            acc11 = __builtin_amdgcn_mfma_f32_16x16x32_bf16(a1, Bf1[kt].v, acc11, 0, 0, 0);
        }

        // transpose + gates in registers (R7/R8-verified)
        f32x4 t00 = xpose4(acc00, lane);
        f32x4 t01 = xpose4(acc01, lane);
        f32x4 t10 = xpose4(acc10, lane);
        f32x4 t11 = xpose4(acc11, lane);
        const bool m0 = (t < L0);
        const bool m1 = (t < L1);
        gatefn(t00, z00, m0, c00, h00);
        gatefn(t01, z01, m0, c01, h01);
        gatefn(t10, z10, m1, c10, h10);
        gatefn(t11, z11, m1, c11, h11);

        hstage[b0 * 32 + u0]        = f2bf(h00);
        hstage[(b0 + 16) * 32 + u0] = f2bf(h10);
        if (v1) {
            hstage[b0 * 32 + u0 + 4]        = f2bf(h01);
            hstage[(b0 + 16) * 32 + u0 + 4] = f2bf(h11);
        }
        __syncthreads();                                  // (2)

        const uint32_t* hs32 = (const uint32_t*)hstage;
        // own chunk -> Hlds for next step (no global round-trip)
#pragma unroll
        for (int s = 0; s < 2; s++) {
            int w = tid + (s << 8);
            int b = w >> 4, j = w & 15;
            Hld32[blk * 1024 + b * 32 + 4 * ((j >> 2) ^ (b & 7)) + (j & 3)] =
                hs32[w];
        }
        // publish tagged chunk: 2 coalesced u64 stores/thread, no flag/drain
        if (ts < TT - 1) {
            unsigned long long* Hdst =
                Hg + (size_t)((ts + 1) & 1) * (KB * 512) + blk * 512;
            const unsigned long long tagv = ((unsigned long long)(ts + 1)) << 32;
            __hip_atomic_store(&Hdst[tid], tagv | hs32[tid],
                               __ATOMIC_RELAXED, __HIP_MEMORY_SCOPE_AGENT);
            __hip_atomic_store(&Hdst[256 + tid], tagv | hs32[256 + tid],
                               __ATOMIC_RELAXED, __HIP_MEMORY_SCOPE_AGENT);
        }

        // private hout stores (coalesced pairs from hstage)
        for (int i = tid; i < BB * 15; i += 256) {
            int b = i / 15, k = i - b * 15;
            *(uint32_t*)&hout[((size_t)(b * TT + t)) * UU + UPB * blk + 2 * k] =
                hs32[b * 16 + k];
        }
    }
}

// ---------------------------------------------------------------------------
// Kernel 4: out[r] = [hf[r] ; hb[r]] @ fc_W + fc_b.
// ---------------------------------------------------------------------------
__global__ __launch_bounds__(256) void fc_out(
    const bf16_t* __restrict__ hf, const bf16_t* __restrict__ hb,
    const void* __restrict__ fcW, const void* __restrict__ fcb,
    void* __restrict__ out, const int* __restrict__ flagp) {

    const int f32m = *flagp;
    __shared__ float W[2 * UU * NTOK];
    __shared__ float bias[NTOK];
    const int tid = threadIdx.x;
    for (int i = tid; i < 2 * UU * NTOK; i += 256) W[i] = ldf(fcW, i, f32m);
    if (tid < NTOK) bias[tid] = ldf(fcb, tid, f32m);
    __syncthreads();

    const int r = blockIdx.x * 256 + tid;
    const bf16_t* hfr = hf + (size_t)r * UU;
    const bf16_t* hbr = hb + (size_t)r * UU;
    float s0 = bias[0], s1 = bias[1], s2 = bias[2];
    for (int u = 0; u < UU; u++) {
        float f = bf2f(hfr[u]);
        s0 += f * W[u * 3 + 0];
        s1 += f * W[u * 3 + 1];
        s2 += f * W[u * 3 + 2];
    }
    for (int u = 0; u < UU; u++) {
        float f = bf2f(hbr[u]);
        s0 += f * W[(UU + u) * 3 + 0];
        s1 += f * W[(UU + u) * 3 + 1];
        s2 += f * W[(UU + u) * 3 + 2];
    }
    if (f32m) {
        float* o = (float*)out;
        o[(size_t)r * 3 + 0] = s0;
        o[(size_t)r * 3 + 1] = s1;
        o[(size_t)r * 3 + 2] = s2;
    } else {
        bf16_t* o = (bf16_t*)out;
        o[(size_t)r * 3 + 0] = f2bf(s0);
        o[(size_t)r * 3 + 1] = f2bf(s1);
        o[(size_t)r * 3 + 2] = f2bf(s2);
    }
}

// ---------------------------------------------------------------------------
extern "C" void kernel_launch(void* const* d_in, const int* in_sizes, int n_in,
                              void* d_out, int out_size, void* d_ws, size_t ws_size,
                              hipStream_t stream) {
    const int* inputs = (const int*)d_in[0];
    const int* seqlen = (const int*)d_in[1];
    const void* emb  = d_in[2];
    const void* Wk_f = d_in[3];
    const void* Wr_f = d_in[4];
    const void* b_f  = d_in[5];
    const void* Wk_b = d_in[6];
    const void* Wr_b = d_in[7];
    const void* b_b  = d_in[8];
    const void* fcW  = d_in[9];
    const void* fcb  = d_in[10];

    // workspace layout (bytes) — total 99,917,504 (< R4-proven 99,923,072)
    char* ws = (char*)d_ws;
    int*      flag   = (int*)(ws + 0);                 // 64 B
    unsigned long long* Hgtag =
              (unsigned long long*)(ws + 64);          // 2*2*10*512*8 = 163,840
    bf16_t*   WrPT_f = (bf16_t*)(ws + 163904);         // 1200*302*2 = 724,800
    bf16_t*   WrPT_b = (bf16_t*)(ws + 888704);         // 724,800
    bf16_t*   zxPf   = (bf16_t*)(ws + 1613504);        // 39,321,600
    bf16_t*   zxPb   = (bf16_t*)(ws + 40935104);       // 39,321,600
    bf16_t*   hfbuf  = (bf16_t*)(ws + 80256704);       // 9,830,400
    bf16_t*   hbbuf  = (bf16_t*)(ws + 90087104);       // 9,830,400
    // WkT/biasP alias hfbuf (used before rec, clobbered after)
    bf16_t*   WkT    = hfbuf;                          // 2*1280*320*2 = 1,638,400
    bf16_t*   biasP  = hfbuf + 2 * WKROWS * WKSTR;     // 5,120

    detect_dtype<<<1, 256, 0, stream>>>((const uint16_t*)emb, flag);
    {
        dim3 grid((G4 * WRROW + 255) / 256, 2);
        prep_wrp<<<grid, 256, 0, stream>>>(Wr_f, Wr_b, WrPT_f, WrPT_b, flag);
    }
    {
        dim3 grid((WKROWS * WKSTR + 255) / 256, 2);
        prep_wkt<<<grid, 256, 0, stream>>>(Wk_f, b_f, Wk_b, b_b, WkT, biasP, flag);
    }
    init_state<<<(2 * 2 * KB * 512 + 255) / 256, 256, 0, stream>>>(Hgtag);
    {
        dim3 grid(10, 256, 2);
        zx_gemm2<<<grid, 256, 0, stream>>>(inputs, emb, WkT, biasP,
                                           zxPf, zxPb, flag);
    }
    lstm_rec7<<<2 * KB, 256, 0, stream>>>(zxPf, zxPb, WrPT_f, WrPT_b, seqlen,
                                          Hgtag, hfbuf, hbbuf);
    fc_out<<<(BB * TT) / 256, 256, 0, stream>>>(hfbuf, hbbuf, fcW, fcb,
                                                d_out, flag);
}

// Round 13
// 2061.831 us; speedup vs baseline: 1.4248x; 1.4248x over previous
//
#include <hip/hip_runtime.h>
#include <stdint.h>

// Bidirectional LSTM.  B=32, T=512, V=32000, D=300, U=300, NT=3.
// R13 = R8 VERBATIM REVERT (verified best: 2065us total / rec 1747us).
// R9-R12 protocol redesigns all regressed; R8's exchange (broadcast flag
// poll + coalesced u64 payload + 3 barriers/step) is the structural floor
// for the forced 10-CU-per-direction L3 all-to-all (Wr=720KB > LDS).

#define BB 32
#define TT 512
#define DD 300
#define UU 300
#define G4 1200   // 4*U
#define NTOK 3

#define KB   10    // rec blocks per direction
#define UPB  30    // units per rec block
#define NCOL 120   // gate-cols per rec block (4*UPB)
#define KTILES 10  // K = 320 (300 padded), 10 tiles of 32
#define HSTR 320   // swizzled LDS row stride (elems)
#define HROW 304   // global H row stride (elems)

#define WKROWS 1280  // WkT padded p-rows
#define WKSTR  320   // WkT padded k-stride

typedef uint16_t bf16_t;
typedef short  s16x8 __attribute__((ext_vector_type(8)));
typedef float  f32x4 __attribute__((ext_vector_type(4)));

union U8 { unsigned long long q[2]; s16x8 v; };

__device__ __forceinline__ float bf2f(uint16_t u) {
    union { uint32_t i; float f; } v; v.i = ((uint32_t)u) << 16; return v.f;
}
__device__ __forceinline__ uint16_t f2bf(float f) {
    union { uint32_t i; float f; } v; v.f = f;
    uint32_t r = v.i + 0x7fffu + ((v.i >> 16) & 1u);   // RNE
    return (uint16_t)(r >> 16);
}
__device__ __forceinline__ float ldf(const void* base, size_t idx, int f32m) {
    return f32m ? ((const float*)base)[idx]
                : bf2f(((const uint16_t*)base)[idx]);
}

// 4x4 transpose across lane bits 0..1 (verified R7)
__device__ __forceinline__ f32x4 xpose4(f32x4 v, int lane) {
    f32x4 t, w, s, r;
    t[0] = __shfl_xor(v[0], 1); t[1] = __shfl_xor(v[1], 1);
    t[2] = __shfl_xor(v[2], 1); t[3] = __shfl_xor(v[3], 1);
    if ((lane & 1) == 0) { w[0]=v[0]; w[1]=t[0]; w[2]=v[2]; w[3]=t[2]; }
    else                 { w[0]=t[1]; w[1]=v[1]; w[2]=t[3]; w[3]=v[3]; }
    s[0] = __shfl_xor(w[0], 2); s[1] = __shfl_xor(w[1], 2);
    s[2] = __shfl_xor(w[2], 2); s[3] = __shfl_xor(w[3], 2);
    if ((lane & 2) == 0) { r[0]=w[0]; r[1]=w[1]; r[2]=s[0]; r[3]=s[1]; }
    else                 { r[0]=s[2]; r[1]=s[3]; r[2]=w[2]; r[3]=w[3]; }
    return r;
}

__device__ __forceinline__ void gatefn(f32x4 zv, uint2 zp, bool m,
                                       float& c, float& h) {
    float zi = zv[0] + bf2f((uint16_t)(zp.x & 0xffff));
    float zf = zv[1] + bf2f((uint16_t)(zp.x >> 16));
    float zg = zv[2] + bf2f((uint16_t)(zp.y & 0xffff));
    float zo = zv[3] + bf2f((uint16_t)(zp.y >> 16));
    float si = 1.f / (1.f + __expf(-zi));
    float sf = 1.f / (1.f + __expf(-zf));
    float so = 1.f / (1.f + __expf(-zo));
    float tg = tanhf(zg);
    float cn = sf * c + si * tg;
    float hn = so * tanhf(cn);
    if (m) { c = cn; h = hn; }
}

// ---------------------------------------------------------------------------
// Kernel 0: dtype detector (f32 vs bf16 inputs).
// ---------------------------------------------------------------------------
__global__ void detect_dtype(const uint16_t* __restrict__ emb_u16,
                             int* __restrict__ flag) {
    __shared__ float red[256];
    const int tid = threadIdx.x;
    float m = 0.f;
    for (int k = tid; k < 4096; k += 256)
        m = fmaxf(m, fabsf(bf2f(emb_u16[2 * k])));
    red[tid] = m;
    __syncthreads();
    for (int s = 128; s > 0; s >>= 1) {
        if (tid < s) red[tid] = fmaxf(red[tid], red[tid + s]);
        __syncthreads();
    }
    if (tid == 0) flag[0] = (red[0] > 1.0e3f) ? 1 : 0;
}

// ---------------------------------------------------------------------------
// Kernel 1: build WrPT[dir][p][k] (rec weights): p = 4u+g, k-major rows of
// length 304 (k>=300 zero).  WrPT[p][k] = Wr[k][g*300+u].
// ---------------------------------------------------------------------------
__global__ void prep_wrp(const void* __restrict__ Wr_f,
                         const void* __restrict__ Wr_b,
                         bf16_t* __restrict__ WrPT_f,
                         bf16_t* __restrict__ WrPT_b,
                         const int* __restrict__ flagp) {
    const int f32m = *flagp;
    int idx = blockIdx.x * 256 + threadIdx.x;          // over 1200*304
    const void* src = blockIdx.y ? Wr_b : Wr_f;
    bf16_t*     dst = blockIdx.y ? WrPT_b : WrPT_f;
    if (idx < G4 * HROW) {
        int p = idx / HROW;
        int k = idx - p * HROW;
        int u = p >> 2, g = p & 3;
        float v = (k < DD) ? ldf(src, (size_t)k * G4 + g * UU + u, f32m) : 0.f;
        dst[idx] = f2bf(v);
    }
}

// ---------------------------------------------------------------------------
// Kernel 1c: build WkT[dir][p][k] (zx weights, permuted+padded) + biasP.
// WkT[p][k] = Wk[k][g*300+u], zero for p>=1200 or k>=300.
// ---------------------------------------------------------------------------
__global__ void prep_wkt(const void* __restrict__ Wk_f, const void* __restrict__ b_f,
                         const void* __restrict__ Wk_b, const void* __restrict__ b_b,
                         bf16_t* __restrict__ WkT, bf16_t* __restrict__ biasP,
                         const int* __restrict__ flagp) {
    const int f32m = *flagp;
    const int dir = blockIdx.y;
    const void* Wk = dir ? Wk_b : Wk_f;
    const void* bs = dir ? b_b  : b_f;
    bf16_t* dst = WkT + (size_t)dir * (WKROWS * WKSTR);
    int idx = blockIdx.x * 256 + threadIdx.x;          // over 1280*320
    if (idx < WKROWS * WKSTR) {
        int p = idx / WKSTR;
        int k = idx - p * WKSTR;
        int u = p >> 2, g = p & 3;
        float v = (p < G4 && k < DD) ? ldf(Wk, (size_t)k * G4 + g * UU + u, f32m)
                                     : 0.f;
        dst[idx] = f2bf(v);
        if (idx < WKROWS) {
            int pp = idx, uu = pp >> 2, gg = pp & 3;
            biasP[dir * WKROWS + idx] =
                (pp < G4) ? f2bf(ldf(bs, gg * UU + uu, f32m)) : (bf16_t)0;
        }
    }
}

// ---------------------------------------------------------------------------
// Kernel 1b: zero H double-buffers and ready flags.
// ---------------------------------------------------------------------------
__global__ void init_state(bf16_t* __restrict__ Hglob, int* __restrict__ flags) {
    int i = blockIdx.x * 256 + threadIdx.x;
    if (i < 2 * 2 * BB * HROW) Hglob[i] = 0;
    if (i < 2 * TT * 16) flags[i] = 0;
}

// ---------------------------------------------------------------------------
// Kernel 2: MFMA zx GEMM.  zx[r][p] = sum_d emb[inputs[r]][d]*WkT[p][d]+b[p].
// Tile M=64 (gathered A in swizzled LDS), N=128 (B-frags direct from WkT/L2).
// grid = (10 Ntiles, 256 Mtiles, 2 dirs), 256 threads.
// ---------------------------------------------------------------------------
#define ZM 64
#define ZN 128
__global__ __launch_bounds__(256, 2) void zx_gemm2(
    const int* __restrict__ inputs, const void* __restrict__ emb,
    const bf16_t* __restrict__ WkTall, const bf16_t* __restrict__ biasP,
    bf16_t* __restrict__ zxf, bf16_t* __restrict__ zxb,
    const int* __restrict__ flagp) {

    const int f32m = *flagp;
    const int dir = blockIdx.z;
    const bf16_t* WkT = WkTall + (size_t)dir * (WKROWS * WKSTR);
    const bf16_t* bp  = biasP + dir * WKROWS;
    bf16_t* out = dir ? zxb : zxf;

    const int tid = threadIdx.x;
    const int pb = blockIdx.x * ZN;           // 0..1152
    const int rowBase = blockIdx.y * ZM;

    __shared__ __align__(16) uint16_t Alds[ZM * HSTR];   // 40,960 B
    __shared__ int rowids[ZM];

    if (tid < ZM) rowids[tid] = inputs[rowBase + tid];
    for (int i = tid; i < ZM * HSTR; i += 256) Alds[i] = 0;
    __syncthreads();

    // stage A gathered: 64 rows x 38 groups of 8, swizzled
    for (int i = tid; i < ZM * 38; i += 256) {
        int r = i / 38, g = i - 38 * r;
        int k0 = g * 8;
        const size_t eb = (size_t)rowids[r] * DD + k0;
        uint16_t tmp[8];
        if (g < 37) {
            if (f32m) {
                const float* ef = (const float*)emb + eb;
#pragma unroll
                for (int e = 0; e < 8; e++) tmp[e] = f2bf(ef[e]);
            } else {
                *(uint4*)tmp = *(const uint4*)((const uint16_t*)emb + eb);
            }
        } else {
#pragma unroll
            for (int e = 0; e < 8; e++) {
                int k = k0 + e;
                tmp[e] = (k < DD)
                    ? (f32m ? f2bf(((const float*)emb)[(size_t)rowids[r] * DD + k])
                            : ((const uint16_t*)emb)[(size_t)rowids[r] * DD + k])
                    : (uint16_t)0;
            }
        }
        *(uint4*)&Alds[r * HSTR + ((g ^ (r & 7)) << 3)] = *(uint4*)tmp;
    }
    __syncthreads();

    const int lane = tid & 63;
    const int wv   = tid >> 6;
    const int q    = lane >> 4;
    const int c16  = lane & 15;
    const int n0   = 32 * wv;
    const int sw7  = c16 & 7;

    f32x4 acc[4][2];
#pragma unroll
    for (int mt = 0; mt < 4; mt++)
        for (int nh = 0; nh < 2; nh++) acc[mt][nh] = (f32x4){0.f,0.f,0.f,0.f};

    const int p0 = pb + n0 + c16;
    const int p1 = p0 + 16;
#pragma unroll
    for (int kt = 0; kt < KTILES; kt++) {
        int k0 = 32 * kt + 8 * q;
        int sw = (((kt * 4 + q) ^ sw7) << 3);
        s16x8 b0 = *(const s16x8*)&WkT[(size_t)p0 * WKSTR + k0];
        s16x8 b1 = *(const s16x8*)&WkT[(size_t)p1 * WKSTR + k0];
#pragma unroll
        for (int mt = 0; mt < 4; mt++) {
            s16x8 af = *(const s16x8*)&Alds[(16 * mt + c16) * HSTR + sw];
            acc[mt][0] = __builtin_amdgcn_mfma_f32_16x16x32_bf16(af, b0, acc[mt][0], 0, 0, 0);
            acc[mt][1] = __builtin_amdgcn_mfma_f32_16x16x32_bf16(af, b1, acc[mt][1], 0, 0, 0);
        }
    }

    __syncthreads();                    // done reading Alds; reuse as C-stage
    float* Cs = (float*)Alds;           // [64][132] f32 = 33,792 B
#pragma unroll
    for (int mt = 0; mt < 4; mt++)
#pragma unroll
        for (int nh = 0; nh < 2; nh++)
#pragma unroll
            for (int r = 0; r < 4; r++)
                Cs[(16 * mt + 4 * q + r) * 132 + n0 + 16 * nh + c16] = acc[mt][nh][r];
    __syncthreads();

    for (int i = tid; i < ZM * (ZN / 2); i += 256) {    // 64x64 u32 pairs
        int r = i >> 6, cc = (i & 63) * 2;
        int p = pb + cc;
        if (p < G4) {
            float v0 = Cs[r * 132 + cc]     + bf2f(bp[p]);
            float v1 = Cs[r * 132 + cc + 1] + bf2f(bp[p + 1]);
            uint32_t pk = (uint32_t)f2bf(v0) | ((uint32_t)f2bf(v1) << 16);
            *(uint32_t*)&out[(size_t)(rowBase + r) * G4 + p] = pk;
        }
    }
}

// ---------------------------------------------------------------------------
// Kernel 3: hybrid MFMA recurrence.  20 blocks (10/dir), 256 thr.
// B-frags + c/h state in registers; H staged via swizzled LDS (coalesced u64
// atomic reload); hstage -> coalesced publish.  3 barriers/step.
// ---------------------------------------------------------------------------
__global__ __launch_bounds__(256, 1) void lstm_rec4(
    const bf16_t* __restrict__ zxf, const bf16_t* __restrict__ zxb,
    const bf16_t* __restrict__ WrPT_f, const bf16_t* __restrict__ WrPT_b,
    const int* __restrict__ seqlen,
    bf16_t* __restrict__ Hglob, int* __restrict__ flags,
    bf16_t* __restrict__ hf, bf16_t* __restrict__ hb) {

    const int blk = blockIdx.x % KB;
    const int dir = blockIdx.x / KB;
    const bf16_t* zx   = dir ? zxb    : zxf;
    const bf16_t* WrPT = dir ? WrPT_b : WrPT_f;
    bf16_t*       hout = dir ? hb : hf;
    bf16_t*       Hg   = Hglob + (size_t)dir * (2 * BB * HROW);
    int*          fbase = flags + dir * (TT * 16);

    __shared__ __align__(16) uint16_t Hlds[BB * HSTR];    // 20,480 B
    __shared__ uint16_t hstage[BB * UPB];                 //  1,920 B

    const int tid  = threadIdx.x;
    const int lane = tid & 63;
    const int wv   = tid >> 6;
    const int q    = lane >> 4;
    const int c16  = lane & 15;
    const int n0   = 32 * wv;
    const int sw7  = c16 & 7;
    const int k4   = c16 >> 2;
    const int j4   = c16 & 3;
    const int u0   = 8 * wv + k4;
    const int b0   = 4 * q + j4;
    const bool v1  = (u0 + 4 < UPB);
    const bool pollme = (lane < KB) && (lane != blk);

    // one-time: zero Hlds (pad groups 38,39 must read 0), B-frags to regs
    for (int i = tid; i < BB * HSTR; i += 256) Hlds[i] = 0;
    U8 Bf0[KTILES], Bf1[KTILES];
#pragma unroll
    for (int kt = 0; kt < KTILES; kt++) {
        int k0 = 32 * kt + 8 * q;
        int col0 = n0 + c16, col1 = n0 + 16 + c16;
        U8 z; z.q[0] = 0; z.q[1] = 0;
        Bf0[kt] = z; Bf1[kt] = z;
        if (k0 < 304) {
            if (col0 < NCOL)
                Bf0[kt].v = *(const s16x8*)&WrPT[(size_t)(NCOL * blk + col0) * HROW + k0];
            if (col1 < NCOL)
                Bf1[kt].v = *(const s16x8*)&WrPT[(size_t)(NCOL * blk + col1) * HROW + k0];
        }
    }
    float c00 = 0.f, c01 = 0.f, c10 = 0.f, c11 = 0.f;
    float h00 = 0.f, h01 = 0.f, h10 = 0.f, h11 = 0.f;
    const int L0 = seqlen[b0];
    const int L1 = seqlen[b0 + 16];
    __syncthreads();

    for (int ts = 0; ts < TT; ts++) {
        const int t = dir ? (TT - 1 - ts) : ts;

        // zx prefetch (overlaps the flag wait)
        const size_t zr0 = ((size_t)(b0 * TT + t)) * G4 + NCOL * blk;
        const size_t zr1 = ((size_t)((b0 + 16) * TT + t)) * G4 + NCOL * blk;
        uint2 z00 = *(const uint2*)&zx[zr0 + 4 * u0];
        uint2 z10 = *(const uint2*)&zx[zr1 + 4 * u0];
        uint2 z01 = {0, 0}, z11 = {0, 0};
        if (v1) {
            z01 = *(const uint2*)&zx[zr0 + 4 * (u0 + 4)];
            z11 = *(const uint2*)&zx[zr1 + 4 * (u0 + 4)];
        }

        if (ts > 0) {
            int* fl = fbase + (ts - 1) * 16;
            for (;;) {
                int v = pollme ? __hip_atomic_load(&fl[lane], __ATOMIC_RELAXED,
                                                   __HIP_MEMORY_SCOPE_AGENT)
                               : 1;
                if (__all(v != 0)) break;
                __builtin_amdgcn_s_sleep(1);
            }
        }

        // coalesced pipelined H reload -> swizzled Hlds (R6-verified)
        const unsigned long long* Hsrc64 =
            (const unsigned long long*)(Hg + (size_t)(ts & 1) * (BB * HROW));
        unsigned long long hv[10];
#pragma unroll
        for (int k = 0; k < 9; k++)
            hv[k] = __hip_atomic_load(&Hsrc64[tid + 256 * k], __ATOMIC_RELAXED,
                                      __HIP_MEMORY_SCOPE_AGENT);
        if (tid < 128)
            hv[9] = __hip_atomic_load(&Hsrc64[2304 + tid], __ATOMIC_RELAXED,
                                      __HIP_MEMORY_SCOPE_AGENT);
#pragma unroll
        for (int k = 0; k < 9; k++) {
            int i = tid + 256 * k;
            int b = i / 76, x = i - 76 * b;
            *(unsigned long long*)
                &Hlds[b * HSTR + ((((x >> 1) ^ (b & 7)) << 3) | ((x & 1) << 2))]
                = hv[k];
        }
        if (tid < 128) {
            int i = 2304 + tid;
            int b = i / 76, x = i - 76 * b;
            *(unsigned long long*)
                &Hlds[b * HSTR + ((((x >> 1) ^ (b & 7)) << 3) | ((x & 1) << 2))]
                = hv[9];
        }
        __syncthreads();                                  // (1)

        // MFMA: A from Hlds (swizzled), B from registers
        f32x4 acc00 = {0.f,0.f,0.f,0.f}, acc01 = {0.f,0.f,0.f,0.f};
        f32x4 acc10 = {0.f,0.f,0.f,0.f}, acc11 = {0.f,0.f,0.f,0.f};
#pragma unroll
        for (int kt = 0; kt < KTILES; kt++) {
            int sw = (((kt * 4 + q) ^ sw7) << 3);
            s16x8 a0 = *(const s16x8*)&Hlds[c16 * HSTR + sw];
            s16x8 a1 = *(const s16x8*)&Hlds[(c16 + 16) * HSTR + sw];
            acc00 = __builtin_amdgcn_mfma_f32_16x16x32_bf16(a0, Bf0[kt].v, acc00, 0, 0, 0);
            acc01 = __builtin_amdgcn_mfma_f32_16x16x32_bf16(a0, Bf1[kt].v, acc01, 0, 0, 0);
            acc10 = __builtin_amdgcn_mfma_f32_16x16x32_bf16(a1, Bf0[kt].v, acc10, 0, 0, 0);
            acc11 = __builtin_amdgcn_mfma_f32_16x16x32_bf16(a1, Bf1[kt].v, acc11, 0, 0, 0);
        }

        // transpose + gates in registers (R7-verified mapping)
        f32x4 t00 = xpose4(acc00, lane);
        f32x4 t01 = xpose4(acc01, lane);
        f32x4 t10 = xpose4(acc10, lane);
        f32x4 t11 = xpose4(acc11, lane);
        const bool m0 = (t < L0);
        const bool m1 = (t < L1);
        gatefn(t00, z00, m0, c00, h00);
        gatefn(t01, z01, m0, c01, h01);
        gatefn(t10, z10, m1, c10, h10);
        gatefn(t11, z11, m1, c11, h11);

        hstage[b0 * UPB + u0]        = f2bf(h00);
        hstage[(b0 + 16) * UPB + u0] = f2bf(h10);
        if (v1) {
            hstage[b0 * UPB + u0 + 4]        = f2bf(h01);
            hstage[(b0 + 16) * UPB + u0 + 4] = f2bf(h11);
        }
        __syncthreads();                                  // (2)

        if (ts < TT - 1) {
            bf16_t* Hdst = Hg + (size_t)((ts + 1) & 1) * (BB * HROW);
            for (int i = tid; i < BB * (UPB / 2); i += 256) {   // 480 pairs
                int b = i / (UPB / 2), k = i - b * (UPB / 2);
                uint32_t val = (uint32_t)hstage[b * UPB + 2 * k] |
                               ((uint32_t)hstage[b * UPB + 2 * k + 1] << 16);
                __hip_atomic_store(
                    (uint32_t*)&Hdst[b * HROW + UPB * blk + 2 * k], val,
                    __ATOMIC_RELAXED, __HIP_MEMORY_SCOPE_AGENT);
            }
            __syncthreads();                              // (3) drain
            if (tid == 0)
                __hip_atomic_store(&fbase[ts * 16 + blk], 1, __ATOMIC_RELAXED,
                                   __HIP_MEMORY_SCOPE_AGENT);
        }

        // private hout stores, off the critical path (coalesced from hstage)
        for (int i = tid; i < BB * (UPB / 2); i += 256) {
            int b = i / (UPB / 2), k = i - b * (UPB / 2);
            uint32_t val = (uint32_t)hstage[b * UPB + 2 * k] |
                           ((uint32_t)hstage[b * UPB + 2 * k + 1] << 16);
            *(uint32_t*)&hout[((size_t)(b * TT + t)) * UU + UPB * blk + 2 * k] = val;
        }
    }
}

// ---------------------------------------------------------------------------
// Kernel 4: out[r] = [hf[r] ; hb[r]] @ fc_W + fc_b.
// ---------------------------------------------------------------------------
__global__ __launch_bounds__(256) void fc_out(
    const bf16_t* __restrict__ hf, const bf16_t* __restrict__ hb,
    const void* __restrict__ fcW, const void* __restrict__ fcb,
    void* __restrict__ out, const int* __restrict__ flagp) {

    const int f32m = *flagp;
    __shared__ float W[2 * UU * NTOK];
    __shared__ float bias[NTOK];
    const int tid = threadIdx.x;
    for (int i = tid; i < 2 * UU * NTOK; i += 256) W[i] = ldf(fcW, i, f32m);
    if (tid < NTOK) bias[tid] = ldf(fcb, tid, f32m);
    __syncthreads();

    const int r = blockIdx.x * 256 + tid;
    const bf16_t* hfr = hf + (size_t)r * UU;
    const bf16_t* hbr = hb + (size_t)r * UU;
    float s0 = bias[0], s1 = bias[1], s2 = bias[2];
    for (int u = 0; u < UU; u++) {
        float f = bf2f(hfr[u]);
        s0 += f * W[u * 3 + 0];
        s1 += f * W[u * 3 + 1];
        s2 += f * W[u * 3 + 2];
    }
    for (int u = 0; u < UU; u++) {
        float f = bf2f(hbr[u]);
        s0 += f * W[(UU + u) * 3 + 0];
        s1 += f * W[(UU + u) * 3 + 1];
        s2 += f * W[(UU + u) * 3 + 2];
    }
    if (f32m) {
        float* o = (float*)out;
        o[(size_t)r * 3 + 0] = s0;
        o[(size_t)r * 3 + 1] = s1;
        o[(size_t)r * 3 + 2] = s2;
    } else {
        bf16_t* o = (bf16_t*)out;
        o[(size_t)r * 3 + 0] = f2bf(s0);
        o[(size_t)r * 3 + 1] = f2bf(s1);
        o[(size_t)r * 3 + 2] = f2bf(s2);
    }
}

// ---------------------------------------------------------------------------
extern "C" void kernel_launch(void* const* d_in, const int* in_sizes, int n_in,
                              void* d_out, int out_size, void* d_ws, size_t ws_size,
                              hipStream_t stream) {
    const int* inputs = (const int*)d_in[0];
    const int* seqlen = (const int*)d_in[1];
    const void* emb  = d_in[2];
    const void* Wk_f = d_in[3];
    const void* Wr_f = d_in[4];
    const void* b_f  = d_in[5];
    const void* Wk_b = d_in[6];
    const void* Wr_b = d_in[7];
    const void* b_b  = d_in[8];
    const void* fcW  = d_in[9];
    const void* fcb  = d_in[10];

    // workspace layout (bytes)
    char* ws = (char*)d_ws;
    int*    flag   = (int*)(ws + 0);                 // 64 B
    int*    flags  = (int*)(ws + 64);                // 65,536
    bf16_t* Hglob  = (bf16_t*)(ws + 65664);          // 77,824
    bf16_t* WrPT_f = (bf16_t*)(ws + 143488);         // 729,600
    bf16_t* WrPT_b = (bf16_t*)(ws + 873088);         // 729,600
    bf16_t* zxPf   = (bf16_t*)(ws + 1602688);        // 39,321,600
    bf16_t* zxPb   = (bf16_t*)(ws + 40924288);       // 39,321,600
    bf16_t* hfbuf  = (bf16_t*)(ws + 80245888);       // 9,830,400
    bf16_t* hbbuf  = (bf16_t*)(ws + 90076288);       // 9,830,400 -> 99,906,688
    // WkT/biasP alias hfbuf: consumed by zx_gemm2 (before rec), clobbered by rec
    bf16_t* WkT    = hfbuf;                          // 2*1280*320*2 = 1,638,400
    bf16_t* biasP  = hfbuf + 2 * WKROWS * WKSTR;     // 5,120

    detect_dtype<<<1, 256, 0, stream>>>((const uint16_t*)emb, flag);
    {
        dim3 grid((G4 * HROW + 255) / 256, 2);
        prep_wrp<<<grid, 256, 0, stream>>>(Wr_f, Wr_b, WrPT_f, WrPT_b, flag);
    }
    {
        dim3 grid((WKROWS * WKSTR + 255) / 256, 2);
        prep_wkt<<<grid, 256, 0, stream>>>(Wk_f, b_f, Wk_b, b_b, WkT, biasP, flag);
    }
    init_state<<<64, 256, 0, stream>>>(Hglob, flags);
    {
        dim3 grid(10, 256, 2);
        zx_gemm2<<<grid, 256, 0, stream>>>(inputs, emb, WkT, biasP,
                                           zxPf, zxPb, flag);
    }
    lstm_rec4<<<2 * KB, 256, 0, stream>>>(zxPf, zxPb, WrPT_f, WrPT_b, seqlen,
                                          Hglob, flags, hfbuf, hbbuf);
    fc_out<<<(BB * TT) / 256, 256, 0, stream>>>(hfbuf, hbbuf, fcW, fcb,
                                                d_out, flag);
}